// Round 9
// baseline (2764.516 us; speedup 1.0000x reference)
//
#include <hip/hip_runtime.h>

#define N_ATOMS   200000
#define N_EDGESC  400000
#define HID       256
#define NGRAPH    8000

typedef __attribute__((ext_vector_type(8))) short bf16x8;
typedef __attribute__((ext_vector_type(4))) float f32x4;

__device__ inline ushort bfc(float x) {
    union { float f; unsigned u; } u; u.f = x;
    unsigned r = u.u + 0x7fff + ((u.u >> 16) & 1);
    return (ushort)(r >> 16);
}
__device__ inline float b2f(ushort u) {
    union { unsigned u; float f; } x; x.u = ((unsigned)u) << 16; return x.f;
}
__device__ inline float u2f(unsigned u) {
    union { unsigned u; float f; } x; x.u = u; return x.f;
}
// pack two f32 -> two bf16 in one u32 (lo=a, hi=b), single VALU op
__device__ inline unsigned pk2(float a, float b) {
    unsigned r;
    asm volatile("v_cvt_pk_bf16_f32 %0, %1, %2" : "=v"(r) : "v"(a), "v"(b));
    return r;
}
__device__ inline float relu(float v) { return v > 0.f ? v : 0.f; }

// ---------------- weight prep: f32 -> bf16 padded layouts ----------------
__global__ void prep_weights(const float* __restrict__ Wi, const float* __restrict__ Wh,
                             const float* __restrict__ Wo, ushort* __restrict__ Wib,
                             ushort* __restrict__ Whb, ushort* __restrict__ Wob) {
    int i = blockIdx.x * 256 + threadIdx.x;
    if (i < 256 * 256) Whb[i] = bfc(Wh[i]);
    if (i < 256 * 192) {
        int t = i / 192, k = i % 192;
        float v = 0.f;
        if (k < 133) v = Wi[t * 147 + k];
        else if (k >= 136 && k < 150) v = Wi[t * 147 + 133 + (k - 136)];
        Wib[i] = bfc(v);
    }
    if (i < 256 * 448) {
        int t = i / 448, k = i % 448;
        float v = 0.f;
        if (k < 133) v = Wo[t * 389 + k];
        else if (k >= 136 && k < 392) v = Wo[t * 389 + 133 + (k - 136)];
        Wob[i] = bfc(v);
    }
}

// ---------------- CSR build ----------------
__global__ void count_kernel(const int* __restrict__ dst, int* __restrict__ cnt, int n) {
    int i = blockIdx.x * blockDim.x + threadIdx.x;
    if (i < n) atomicAdd(&cnt[dst[i]], 1);
}

// parallel scan, 3 stages
__global__ void scan_part(const int* __restrict__ deg, int* __restrict__ part, int n) {
    __shared__ int sm[256];
    int t = threadIdx.x;
    int i = blockIdx.x * 256 + t;
    int v = (i < n) ? deg[i] : 0;
    sm[t] = v; __syncthreads();
    for (int off = 128; off > 0; off >>= 1) {
        if (t < off) sm[t] += sm[t + off];
        __syncthreads();
    }
    if (t == 0) part[blockIdx.x] = sm[0];
}

__global__ void scan_tops(int* __restrict__ part, int nb, int* __restrict__ offs) {
    __shared__ int sm[1024];
    int t = threadIdx.x;
    int v = (t < nb) ? part[t] : 0;
    sm[t] = v; __syncthreads();
    for (int off = 1; off < 1024; off <<= 1) {
        int x = (t >= off) ? sm[t - off] : 0;
        __syncthreads();
        sm[t] += x;
        __syncthreads();
    }
    if (t < nb) part[t] = sm[t] - v;     // exclusive block base
    if (t == 0) offs[N_ATOMS] = N_EDGESC; // total degree is exactly N_EDGES
}

__global__ void scan_fin(const int* __restrict__ deg, const int* __restrict__ part,
                         int* __restrict__ offs, int* __restrict__ cursor, int n) {
    __shared__ int sm[256];
    int t = threadIdx.x;
    int i = blockIdx.x * 256 + t;
    int v = (i < n) ? deg[i] : 0;
    sm[t] = v; __syncthreads();
    for (int off = 1; off < 256; off <<= 1) {
        int x = (t >= off) ? sm[t - off] : 0;
        __syncthreads();
        sm[t] += x;
        __syncthreads();
    }
    if (i < n) {
        int excl = sm[t] - v + part[blockIdx.x];
        offs[i] = excl;
        cursor[i] = excl;
    }
}

__global__ void fill_kernel(const int* __restrict__ dst, int* __restrict__ cursor,
                            int* __restrict__ eids, int n) {
    int i = blockIdx.x * blockDim.x + threadIdx.x;
    if (i < n) {
        int p = atomicAdd(&cursor[dst[i]], 1);
        eids[p] = i;
    }
}

// h0 = relu([V[src];E] @ Wib^T), K=192, LDS row stride 384B. Output bf16.
// Swapped MFMA: D row = channel, D col = edge -> vectorized epilogue.
__global__ __launch_bounds__(256) void h0_mfma(const float* __restrict__ V,
                                               const float* __restrict__ E,
                                               const ushort* __restrict__ Wib,
                                               const int* __restrict__ src,
                                               ushort* __restrict__ h0b) {
    __shared__ char lds[64 * 384];
    int t = threadIdx.x;
    int e0 = blockIdx.x * 64;
#pragma unroll
    for (int i = 0; i < 6; i++) {
        int c = t + i * 256;
        int e = c / 24, kc = c % 24;
        int ge = e0 + e;
        int s = src[ge];
        int k0 = kc * 8;
        float xs[8];
#pragma unroll
        for (int j = 0; j < 8; j++) {
            int k = k0 + j;
            float x;
            if (k < 133) x = V[(size_t)s * 133 + k];
            else if (k < 136) x = 0.f;
            else if (k < 150) x = E[(size_t)ge * 14 + (k - 136)];
            else x = 0.f;
            xs[j] = x;
        }
        uint4 o;
        o.x = pk2(xs[0], xs[1]); o.y = pk2(xs[2], xs[3]);
        o.z = pk2(xs[4], xs[5]); o.w = pk2(xs[6], xs[7]);
        int addr = (e * 384 + k0 * 2) ^ ((e & 7) << 4);
        *(uint4*)(lds + addr) = o;
    }
    __syncthreads();
    int lane = t & 63, w = t >> 6;
    int n0 = w * 64;
    int lq = lane >> 4, lr = lane & 15;
    f32x4 acc[4][4];
#pragma unroll
    for (int mt = 0; mt < 4; mt++)
#pragma unroll
        for (int nt = 0; nt < 4; nt++) acc[mt][nt] = {0.f, 0.f, 0.f, 0.f};
    for (int ks = 0; ks < 6; ks++) {
        int kk = ks * 32 + lq * 8;
        bf16x8 af[4], bfr[4];
#pragma unroll
        for (int mt = 0; mt < 4; mt++) {
            int row = mt * 16 + lr;
            int addr = (row * 384 + kk * 2) ^ ((row & 7) << 4);
            af[mt] = *(const bf16x8*)(lds + addr);
        }
#pragma unroll
        for (int nt = 0; nt < 4; nt++) {
            int col = n0 + nt * 16 + lr;
            bfr[nt] = *(const bf16x8*)&Wib[col * 192 + kk];
        }
#pragma unroll
        for (int mt = 0; mt < 4; mt++)
#pragma unroll
            for (int nt = 0; nt < 4; nt++)   // swapped: A=W, B=x
                acc[mt][nt] = __builtin_amdgcn_mfma_f32_16x16x32_bf16(bfr[nt], af[mt], acc[mt][nt], 0, 0, 0);
    }
#pragma unroll
    for (int mt = 0; mt < 4; mt++)
#pragma unroll
        for (int nt = 0; nt < 4; nt++) {
            int row = e0 + mt * 16 + lr;            // edge
            int chan = n0 + nt * 16 + lq * 4;       // 4 consecutive channels
            float v0 = relu(acc[mt][nt][0]), v1 = relu(acc[mt][nt][1]);
            float v2 = relu(acc[mt][nt][2]), v3 = relu(acc[mt][nt][3]);
            uint2 o; o.x = pk2(v0, v1); o.y = pk2(v2, v3);
            *(uint2*)&h0b[(size_t)row * HID + chan] = o;
        }
}

// mp: h_new = relu((mta[src] - w[rev]*h[rev]) @ Whb^T + h0)
// 512 threads, 8 waves (2 row-tiles x 4 col-tiles), swapped MFMA.
template <int FINAL>
__global__ __launch_bounds__(512) void mp_mfma(const ushort* __restrict__ mta_b,
                                               const ushort* __restrict__ h0b,
                                               const ushort* __restrict__ Whb,
                                               const float* __restrict__ weight,
                                               const int* __restrict__ src,
                                               const int* __restrict__ rev,
                                               const ushort* __restrict__ hr_b,
                                               ushort* __restrict__ hw_b,
                                               float* __restrict__ hw_f) {
    __shared__ char lds[64 * 512];
    int t = threadIdx.x;
    int e0 = blockIdx.x * 64;
    // staging: 8 threads per edge, 4 chunks (16B) each from mta row + h row
    int e = t >> 3, q = t & 7;
    int ge = e0 + e;
    int s = src[ge], r = rev[ge];
    float nwr = -weight[r];
    const uint4* mrow = (const uint4*)&mta_b[(size_t)s * HID];  // 32 x 16B chunks
    const uint4* hrow = (const uint4*)&hr_b[(size_t)r * HID];
    uint4 ma[4], ha[4];
#pragma unroll
    for (int i = 0; i < 4; i++) ma[i] = mrow[q + 8 * i];
#pragma unroll
    for (int i = 0; i < 4; i++) ha[i] = hrow[q + 8 * i];
#pragma unroll
    for (int i = 0; i < 4; i++) {
        int chunk = q + 8 * i;
        uint4 o;
        {
            unsigned mw = ma[i].x, hw = ha[i].x;
            o.x = pk2(fmaf(nwr, u2f(hw << 16), u2f(mw << 16)),
                      fmaf(nwr, u2f(hw & 0xffff0000u), u2f(mw & 0xffff0000u)));
        }
        {
            unsigned mw = ma[i].y, hw = ha[i].y;
            o.y = pk2(fmaf(nwr, u2f(hw << 16), u2f(mw << 16)),
                      fmaf(nwr, u2f(hw & 0xffff0000u), u2f(mw & 0xffff0000u)));
        }
        {
            unsigned mw = ma[i].z, hw = ha[i].z;
            o.z = pk2(fmaf(nwr, u2f(hw << 16), u2f(mw << 16)),
                      fmaf(nwr, u2f(hw & 0xffff0000u), u2f(mw & 0xffff0000u)));
        }
        {
            unsigned mw = ma[i].w, hw = ha[i].w;
            o.w = pk2(fmaf(nwr, u2f(hw << 16), u2f(mw << 16)),
                      fmaf(nwr, u2f(hw & 0xffff0000u), u2f(mw & 0xffff0000u)));
        }
        int addr = (e * 512 + chunk * 16) ^ ((e & 7) << 4);
        *(uint4*)(lds + addr) = o;
    }
    __syncthreads();   // all reads of old h done before any write (rev stays in-block)
    int lane = t & 63, wid = t >> 6;
    int wr = wid >> 2, wc = wid & 3;            // 2x4 wave grid
    int lq = lane >> 4, lr = lane & 15;
    f32x4 acc[2][4];
#pragma unroll
    for (int mt = 0; mt < 2; mt++)
#pragma unroll
        for (int nt = 0; nt < 4; nt++) acc[mt][nt] = {0.f, 0.f, 0.f, 0.f};
    for (int ks = 0; ks < 8; ks++) {
        int kk = ks * 32 + lq * 8;
        bf16x8 af[2], bfr[4];
#pragma unroll
        for (int mt = 0; mt < 2; mt++) {
            int row = wr * 32 + mt * 16 + lr;
            int addr = (row * 512 + kk * 2) ^ ((row & 7) << 4);
            af[mt] = *(const bf16x8*)(lds + addr);
        }
#pragma unroll
        for (int nt = 0; nt < 4; nt++) {
            int col = wc * 64 + nt * 16 + lr;
            bfr[nt] = *(const bf16x8*)&Whb[col * 256 + kk];
        }
#pragma unroll
        for (int mt = 0; mt < 2; mt++)
#pragma unroll
            for (int nt = 0; nt < 4; nt++)   // swapped: A=W, B=x
                acc[mt][nt] = __builtin_amdgcn_mfma_f32_16x16x32_bf16(bfr[nt], af[mt], acc[mt][nt], 0, 0, 0);
    }
#pragma unroll
    for (int mt = 0; mt < 2; mt++)
#pragma unroll
        for (int nt = 0; nt < 4; nt++) {
            int row = e0 + wr * 32 + mt * 16 + lr;      // edge
            int chan = wc * 64 + nt * 16 + lq * 4;      // 4 consecutive channels
            size_t idx = (size_t)row * HID + chan;
            uint2 h0v = *(const uint2*)&h0b[idx];
            float v0 = relu(acc[mt][nt][0] + u2f(h0v.x << 16));
            float v1 = relu(acc[mt][nt][1] + u2f(h0v.x & 0xffff0000u));
            float v2 = relu(acc[mt][nt][2] + u2f(h0v.y << 16));
            float v3 = relu(acc[mt][nt][3] + u2f(h0v.y & 0xffff0000u));
            if (FINAL) {
                float4 o; o.x = v0; o.y = v1; o.z = v2; o.w = v3;
                *(float4*)&hw_f[idx] = o;
            } else {
                uint2 o; o.x = pk2(v0, v1); o.y = pk2(v2, v3);
                *(uint2*)&hw_b[idx] = o;
            }
        }
}

// out: h_atom = relu([V;mfin] @ Wob^T + b), K=448, mfin bf16, output f32
__global__ __launch_bounds__(256) void out_mfma(const float* __restrict__ V,
                                                const ushort* __restrict__ mfin,
                                                const ushort* __restrict__ Wob,
                                                const float* __restrict__ bias,
                                                float* __restrict__ h_atom) {
    __shared__ char lds[64 * 896];
    int t = threadIdx.x;
    int a0 = blockIdx.x * 64;
#pragma unroll
    for (int i = 0; i < 14; i++) {
        int c = t + i * 256;
        int e = c / 56, kc = c % 56;
        int a = a0 + e;
        int k0 = kc * 8;
        float xs[8];
#pragma unroll
        for (int j = 0; j < 8; j++) {
            int k = k0 + j;
            float x;
            if (k < 133) x = V[(size_t)a * 133 + k];
            else if (k < 136) x = 0.f;
            else if (k < 392) x = b2f(mfin[(size_t)a * HID + (k - 136)]);
            else x = 0.f;
            xs[j] = x;
        }
        uint4 o;
        o.x = pk2(xs[0], xs[1]); o.y = pk2(xs[2], xs[3]);
        o.z = pk2(xs[4], xs[5]); o.w = pk2(xs[6], xs[7]);
        int addr = (e * 896 + k0 * 2) ^ ((e & 7) << 4);
        *(uint4*)(lds + addr) = o;
    }
    __syncthreads();
    int lane = t & 63, w = t >> 6;
    int n0 = w * 64;
    int lq = lane >> 4, lr = lane & 15;
    float4 b4[4];
#pragma unroll
    for (int nt = 0; nt < 4; nt++)
        b4[nt] = *(const float4*)&bias[n0 + nt * 16 + lq * 4];
    f32x4 acc[4][4];
#pragma unroll
    for (int mt = 0; mt < 4; mt++)
#pragma unroll
        for (int nt = 0; nt < 4; nt++) acc[mt][nt] = {0.f, 0.f, 0.f, 0.f};
    for (int ks = 0; ks < 14; ks++) {
        int kk = ks * 32 + lq * 8;
        bf16x8 af[4], bfr[4];
#pragma unroll
        for (int mt = 0; mt < 4; mt++) {
            int row = mt * 16 + lr;
            int addr = (row * 896 + kk * 2) ^ ((row & 7) << 4);
            af[mt] = *(const bf16x8*)(lds + addr);
        }
#pragma unroll
        for (int nt = 0; nt < 4; nt++) {
            int col = n0 + nt * 16 + lr;
            bfr[nt] = *(const bf16x8*)&Wob[col * 448 + kk];
        }
#pragma unroll
        for (int mt = 0; mt < 4; mt++)
#pragma unroll
            for (int nt = 0; nt < 4; nt++)   // swapped
                acc[mt][nt] = __builtin_amdgcn_mfma_f32_16x16x32_bf16(bfr[nt], af[mt], acc[mt][nt], 0, 0, 0);
    }
#pragma unroll
    for (int mt = 0; mt < 4; mt++)
#pragma unroll
        for (int nt = 0; nt < 4; nt++) {
            int row = a0 + mt * 16 + lr;
            int chan = n0 + nt * 16 + lq * 4;
            float4 o;
            o.x = relu(acc[mt][nt][0] + b4[nt].x);
            o.y = relu(acc[mt][nt][1] + b4[nt].y);
            o.z = relu(acc[mt][nt][2] + b4[nt].z);
            o.w = relu(acc[mt][nt][3] + b4[nt].w);
            *(float4*)&h_atom[(size_t)row * HID + chan] = o;
        }
}

// ---------------- seg reduce: bf16 in (weighted), bf16 out ----------------
__global__ void seg_reduce_b(const ushort* __restrict__ h, const float* __restrict__ weight,
                             const int* __restrict__ offs, const int* __restrict__ eids,
                             ushort* __restrict__ out) {
    int t = threadIdx.x;
    int a = blockIdx.x * 4 + (t >> 6);
    int c = t & 63;
    int lo = offs[a], hi = offs[a + 1];
    float acc0 = 0.f, acc1 = 0.f, acc2 = 0.f, acc3 = 0.f;
    for (int i = lo; i < hi; i++) {
        int e = eids[i];
        float w = weight[e];
        uint2 x = ((const uint2*)&h[(size_t)e * HID])[c];
        acc0 += w * u2f(x.x << 16); acc1 += w * u2f(x.x & 0xffff0000u);
        acc2 += w * u2f(x.y << 16); acc3 += w * u2f(x.y & 0xffff0000u);
    }
    uint2 o; o.x = pk2(acc0, acc1); o.y = pk2(acc2, acc3);
    ((uint2*)&out[(size_t)a * HID])[c] = o;
}

// final: f32 in (unweighted), bf16 out
__global__ void seg_reduce_f(const float* __restrict__ h,
                             const int* __restrict__ offs, const int* __restrict__ eids,
                             ushort* __restrict__ out) {
    int t = threadIdx.x;
    int a = blockIdx.x * 4 + (t >> 6);
    int c = t & 63;
    int lo = offs[a], hi = offs[a + 1];
    float4 acc = {0.f, 0.f, 0.f, 0.f};
    for (int i = lo; i < hi; i++) {
        int e = eids[i];
        float4 x = ((const float4*)&h[(size_t)e * HID])[c];
        acc.x += x.x; acc.y += x.y; acc.z += x.z; acc.w += x.w;
    }
    uint2 o; o.x = pk2(acc.x, acc.y); o.y = pk2(acc.z, acc.w);
    ((uint2*)&out[(size_t)a * HID])[c] = o;
}

// ---------------- mol_vecs ----------------
__global__ void mol_kernel(const float* __restrict__ h_atom, const int* __restrict__ batch,
                           float* __restrict__ mol) {
    int g = blockIdx.x;
    int t = threadIdx.x;
    __shared__ int s_lo, s_hi;
    if (t == 0) {
        int lo = 0, hi = N_ATOMS;
        while (lo < hi) { int mid = (lo + hi) >> 1; if (batch[mid] < g) lo = mid + 1; else hi = mid; }
        s_lo = lo;
        int lo2 = lo, hi2 = N_ATOMS;
        while (lo2 < hi2) { int mid = (lo2 + hi2) >> 1; if (batch[mid] < g + 1) lo2 = mid + 1; else hi2 = mid; }
        s_hi = lo2;
    }
    __syncthreads();
    float acc = 0.f;
    for (int a = s_lo; a < s_hi; a++) acc += h_atom[(size_t)a * HID + t];
    mol[(size_t)g * HID + t] = acc;
}

__global__ void batchf_kernel(const int* __restrict__ batch, float* __restrict__ outb, int n) {
    int i = blockIdx.x * blockDim.x + threadIdx.x;
    if (i < n) outb[i] = (float)batch[i];
}

extern "C" void kernel_launch(void* const* d_in, const int* in_sizes, int n_in,
                              void* d_out, int out_size, void* d_ws, size_t ws_size,
                              hipStream_t stream) {
    const float* V      = (const float*)d_in[0];
    const float* E      = (const float*)d_in[1];
    const float* weight = (const float*)d_in[2];
    const float* W_i    = (const float*)d_in[3];
    const float* W_h    = (const float*)d_in[4];
    const float* W_o    = (const float*)d_in[5];
    const float* W_b    = (const float*)d_in[6];
    const int*   eidx   = (const int*)d_in[7];
    const int*   src    = eidx;
    const int*   dst    = eidx + N_EDGESC;
    const int*   rev    = (const int*)d_in[8];
    const int*   batch  = (const int*)d_in[9];

    float* out     = (float*)d_out;
    float* o_hatom = out;                                  // 200000*256
    float* o_batch = out + (size_t)51200000;               // 200000
    float* o_mol   = out + (size_t)51400000;               // 8000*256
    float* o_h     = out + (size_t)53448000;               // 400000*256

    char* base = (char*)d_ws;
    ushort* h0b    = (ushort*)(base);                      // 204,800,000 B
    ushort* h_b    = (ushort*)(base + 204800000ull);       // 204,800,000 B
    ushort* mta_b  = (ushort*)(base + 409600000ull);       // 102,400,000 B
    ushort* Whb    = (ushort*)(base + 512000000ull);       // 131,072 B
    ushort* Wib    = (ushort*)(base + 512131072ull);       // 98,304 B
    ushort* Wob    = (ushort*)(base + 512229376ull);       // 229,376 B
    int*    offs   = (int*)(base + 512458752ull);          // 800,016 B
    int*    cursor = (int*)(base + 513258768ull);          // 800,000 B
    int*    eids   = (int*)(base + 514058768ull);          // 1,600,000 B
    int*    deg    = (int*)(base + 515658768ull);          // 800,000 B
    int*    part   = (int*)(base + 516458768ull);          // 4,096 B

    const int NB = (N_ATOMS + 255) / 256;  // 782 scan blocks

    hipMemsetAsync(deg, 0, N_ATOMS * sizeof(int), stream);

    prep_weights<<<448, 256, 0, stream>>>(W_i, W_h, W_o, Wib, Whb, Wob);
    count_kernel<<<(N_EDGESC + 255) / 256, 256, 0, stream>>>(dst, deg, N_EDGESC);
    scan_part<<<NB, 256, 0, stream>>>(deg, part, N_ATOMS);
    scan_tops<<<1, 1024, 0, stream>>>(part, NB, offs);
    scan_fin<<<NB, 256, 0, stream>>>(deg, part, offs, cursor, N_ATOMS);
    fill_kernel<<<(N_EDGESC + 255) / 256, 256, 0, stream>>>(dst, cursor, eids, N_EDGESC);

    h0_mfma<<<N_EDGESC / 64, 256, 0, stream>>>(V, E, Wib, src, h0b);

    // it 0: h0b -> h_b ; it 1: h_b -> h_b (in place, race-free) ; it 2: h_b -> o_h (f32)
    seg_reduce_b<<<N_ATOMS / 4, 256, 0, stream>>>(h0b, weight, offs, eids, mta_b);
    mp_mfma<0><<<N_EDGESC / 64, 512, 0, stream>>>(mta_b, h0b, Whb, weight, src, rev, h0b, h_b, nullptr);

    seg_reduce_b<<<N_ATOMS / 4, 256, 0, stream>>>(h_b, weight, offs, eids, mta_b);
    mp_mfma<0><<<N_EDGESC / 64, 512, 0, stream>>>(mta_b, h0b, Whb, weight, src, rev, h_b, h_b, nullptr);

    seg_reduce_b<<<N_ATOMS / 4, 256, 0, stream>>>(h_b, weight, offs, eids, mta_b);
    mp_mfma<1><<<N_EDGESC / 64, 512, 0, stream>>>(mta_b, h0b, Whb, weight, src, rev, h_b, nullptr, o_h);

    seg_reduce_f<<<N_ATOMS / 4, 256, 0, stream>>>(o_h, offs, eids, mta_b);
    out_mfma<<<N_ATOMS / 64, 256, 0, stream>>>(V, mta_b, Wob, W_b, o_hatom);
    mol_kernel<<<NGRAPH, 256, 0, stream>>>(o_hatom, batch, o_mol);
    batchf_kernel<<<(N_ATOMS + 255) / 256, 256, 0, stream>>>(batch, o_batch, N_ATOMS);
}